// Round 5
// baseline (1440.072 us; speedup 1.0000x reference)
//
#include <hip/hip_runtime.h>

typedef __bf16 bf16_t;
typedef bf16_t bf16x8 __attribute__((ext_vector_type(8)));
typedef float  f32x4  __attribute__((ext_vector_type(4)));

#define MFMA16(A, B, C) __builtin_amdgcn_mfma_f32_16x16x32_bf16((A), (B), (C), 0, 0, 0)

static constexpr int KEXT   = 288;  // 256 h | 3 x | 1 ones(bias) | 28 zero pad
static constexpr int HS     = 296;  // LDS row stride (592 B: 16B-aligned, 2-way bank alias only)
static constexpr int TSTEPS = 128;
static constexpr int TILE_B = 16;   // grid 256 -> 1 block/CU

// ws layout (bf16 elements)
static constexpr int WALL_OFF = 0;                    // [1152][288] gates(1024) + Wo1ext(128)
static constexpr int W2E_OFF  = 1152 * 288;           // [512][288]  encoder layer2 (+b2 col)
static constexpr int WO2E_OFF = W2E_OFF + 512 * 288;  // [16][128]   Wo2 padded
static constexpr int WS_ELEMS = WO2E_OFF + 16 * 128;

// ---------------- prep: pack weights bf16 (ws re-poisoned every launch) ----------------
__global__ __launch_bounds__(256) void prep_kernel(
    const float* __restrict__ W2,  const float* __restrict__ b2,
    const float* __restrict__ Wih, const float* __restrict__ Whh,
    const float* __restrict__ bih, const float* __restrict__ bhh,
    const float* __restrict__ Wo1, const float* __restrict__ bo1,
    const float* __restrict__ Wo2, bf16_t* __restrict__ ws)
{
    int idx = blockIdx.x * 256 + threadIdx.x;
    if (idx < 1152 * 288) {
        int r = idx / 288, k = idx - r * 288;
        float v = 0.f;
        if (r < 1024) {                       // gate rows: i f g o (256 each)
            if (k < 256)       v = Whh[r * 256 + k];
            else if (k < 259)  v = Wih[r * 3 + (k - 256)];
            else if (k == 259) v = bih[r] + bhh[r];
        } else {                              // Wo1 rows (zeros at x cols, bo1 at ones col)
            int q = r - 1024;
            if (k < 256)       v = Wo1[q * 256 + k];
            else if (k == 259) v = bo1[q];
        }
        ws[WALL_OFF + idx] = (bf16_t)v;
    } else if (idx < W2E_OFF + 512 * 288) {
        int j = idx - W2E_OFF;
        int u = j / 288, k = j - u * 288;
        float v = 0.f;
        if (k < 256)       v = W2[u * 256 + k];
        else if (k == 259) v = b2[u];
        ws[idx] = (bf16_t)v;
    } else if (idx < WS_ELEMS) {
        int j = idx - WO2E_OFF;
        int d = j >> 7, q = j & 127;
        ws[idx] = (bf16_t)((d < 3) ? Wo2[d * 128 + q] : 0.f);
    }
}

__device__ __forceinline__ float sigm(float x) { return 1.f / (1.f + __expf(-x)); }
__device__ __forceinline__ float tanh_f(float x) {
    float a = fminf(fmaxf(x, -15.f), 15.f);
    float e = __expf(2.f * a);
    return (e - 1.f) / (e + 1.f);
}
__device__ __forceinline__ unsigned pk2(float a, float b) {
    union { bf16_t h[2]; unsigned u; } x;
    x.h[0] = (bf16_t)a; x.h[1] = (bf16_t)b; return x.u;
}

// ---------------- main: 256 blocks x 512 thr; block owns 16 batches end-to-end.
// amdgpu_waves_per_eu(2,2) pins allocator budget to 256 VGPR/wave (occupancy is
// LDS-bound at 1 block/CU anyway). Resident: gates i,f for dims [32wv,32wv+32)
// = af[2][2][9] = 144 VGPR. Gates g,o streamed from L2 with 2-deep prefetch.
__attribute__((amdgpu_waves_per_eu(2, 2)))
__global__ __launch_bounds__(512) void lstm_main(
    const float* __restrict__ meta, const float* __restrict__ W1,
    const float* __restrict__ b1,   const float* __restrict__ bo2,
    const bf16_t* __restrict__ ws,  float* __restrict__ out)
{
    __shared__ __align__(16) bf16_t hx[2][TILE_B][HS];  // [h(256)|x(3)|1|pad] double-buffered
    __shared__ __align__(16) bf16_t wo1l[128][HS];      // Wo1ext; aliased as cbuf fp32 in setup
    __shared__ __align__(16) bf16_t wo2l[16][136];
    __shared__ __align__(16) bf16_t zbuf[TILE_B][136];

    const int tid  = threadIdx.x;
    const int wv   = tid >> 6;       // 0..7
    const int lane = tid & 63;
    const int l15  = lane & 15;
    const int quad = lane >> 4;      // 0..3
    const int gb   = blockIdx.x * TILE_B;

    const bf16_t* wall = ws + WALL_OFF;
    const bf16_t* w2e  = ws + W2E_OFF;
    const bf16_t* wo2e = ws + WO2E_OFF;
    const f32x4 zero4 = {0.f, 0.f, 0.f, 0.f};

    // ---- init ext cols of both hx buffers (x0 in buf0; ones col; zero pad) ----
    if (tid < 32) {
        int buf = tid >> 4, b = tid & 15;
        for (int c = 256; c < HS; ++c) {
            float v = 0.f;
            if (c < 259)       v = buf ? 0.f : meta[(size_t)(gb + b) * 7 + (c - 256)];
            else if (c == 259) v = 1.f;
            hx[buf][b][c] = (bf16_t)v;
        }
    }
    // ---- enc1 (VALU, K=7) into hx[1] ----
    {
        int b = tid & 15, j0 = (tid >> 4) * 8;
        float m[7];
        #pragma unroll
        for (int k = 0; k < 7; ++k) m[k] = meta[(size_t)(gb + b) * 7 + k];
        #pragma unroll
        for (int jj = 0; jj < 8; ++jj) {
            int jd = j0 + jj;
            float acc = b1[jd];
            #pragma unroll
            for (int k = 0; k < 7; ++k) acc += W1[jd * 7 + k] * m[k];
            hx[1][b][jd] = (bf16_t)fmaxf(acc, 0.f);
        }
    }
    __syncthreads();

    // ---- enc2 via MFMA: wave wv rows [64wv,64wv+64); rows<256 -> h0(hx[0]), >=256 -> c0(cbuf) ----
    float* cbuf = (float*)&wo1l[0][0];  // fp32 [256][17]
    {
        f32x4 e[4] = {zero4, zero4, zero4, zero4};
        #pragma unroll
        for (int kk = 0; kk < 9; ++kk) {
            int ko = 32 * kk + 8 * quad;
            bf16x8 bf = *(const bf16x8*)&hx[1][l15][ko];
            #pragma unroll
            for (int m = 0; m < 4; ++m) {
                bf16x8 a = *(const bf16x8*)&w2e[(size_t)(64 * wv + 16 * m + l15) * KEXT + ko];
                e[m] = MFMA16(a, bf, e[m]);
            }
        }
        #pragma unroll
        for (int m = 0; m < 4; ++m) {
            int row = 64 * wv + 16 * m + 4 * quad;
            if (row < 256) {  // h0
                *(unsigned*)&hx[0][l15][row]     = pk2(fmaxf(e[m][0], 0.f), fmaxf(e[m][1], 0.f));
                *(unsigned*)&hx[0][l15][row + 2] = pk2(fmaxf(e[m][2], 0.f), fmaxf(e[m][3], 0.f));
            } else {          // c0
                int d = row - 256;
                #pragma unroll
                for (int r = 0; r < 4; ++r)
                    cbuf[(size_t)(d + r) * 17 + l15] = fmaxf(e[m][r], 0.f);
            }
        }
    }
    __syncthreads();

    // ---- c0 -> regs: c[half][r] at dim 32wv+16half+4quad+r, batch l15 ----
    f32x4 c[2];
    #pragma unroll
    for (int half = 0; half < 2; ++half)
        #pragma unroll
        for (int r = 0; r < 4; ++r)
            c[half][r] = cbuf[(size_t)(32 * wv + 16 * half + 4 * quad + r) * 17 + l15];
    __syncthreads();

    // ---- Wo1 -> LDS (overwrites cbuf); Wo2 -> LDS ----
    #pragma unroll
    for (int i = 0; i < 9; ++i) {
        int idx = tid + 512 * i;
        int r = idx / 36, c8 = idx - r * 36;
        *(bf16x8*)&wo1l[r][8 * c8] = *(const bf16x8*)&wall[(size_t)(1024 + r) * KEXT + 8 * c8];
    }
    #pragma unroll
    for (int i = 0; i < 4; ++i) {
        int idx = tid + 512 * i;
        int r = idx >> 7, cc = idx & 127;
        wo2l[r][cc] = wo2e[r * 128 + cc];
    }

    // ---- resident A-frags: gates 0 (i) and 1 (f), dims [32wv,32wv+32): 144 VGPR ----
    bf16x8 af[2][2][9];
    #pragma unroll
    for (int g = 0; g < 2; ++g)
        #pragma unroll
        for (int h = 0; h < 2; ++h)
            #pragma unroll
            for (int kk = 0; kk < 9; ++kk)
                af[g][h][kk] = *(const bf16x8*)
                    &wall[(size_t)(256 * g + 32 * wv + 16 * h + l15) * KEXT + 32 * kk + 8 * quad];

    // streamed base: gates 2 (g), 3 (o)
    const bf16_t* sb = wall + (size_t)(32 * wv + l15) * KEXT + 8 * quad;

    __syncthreads();

    // ================= time loop =================
    for (int t = 0; t < TSTEPS; ++t) {
        const bf16_t (*cur)[HS] = hx[t & 1];
        bf16_t (*nxt)[HS]       = hx[(t + 1) & 1];

        // -- phase 1: gates = [h|x|1] @ Wall^T; i,f from regs; g,o streamed w/ 2-deep prefetch --
        f32x4 acc[4][2];
        #pragma unroll
        for (int g = 0; g < 4; ++g) { acc[g][0] = zero4; acc[g][1] = zero4; }

        bf16x8 s0[4], s1[4];
        #pragma unroll
        for (int i = 0; i < 4; ++i) {
            int g = 2 + (i >> 1), h = i & 1;
            s0[i] = *(const bf16x8*)(sb + (size_t)(256 * g + 16 * h) * KEXT);
        }
        #pragma unroll
        for (int kk = 0; kk < 9; ++kk) {
            int ko = 32 * kk + 8 * quad;
            bf16x8 bf = *(const bf16x8*)&cur[l15][ko];
            if (kk < 8) {   // prefetch next k-slice into the other buffer
                #pragma unroll
                for (int i = 0; i < 4; ++i) {
                    int g = 2 + (i >> 1), h = i & 1;
                    bf16x8 v = *(const bf16x8*)(sb + (size_t)(256 * g + 16 * h) * KEXT + 32 * (kk + 1));
                    if (kk & 1) s0[i] = v; else s1[i] = v;
                }
            }
            #pragma unroll
            for (int h = 0; h < 2; ++h) {
                acc[0][h] = MFMA16(af[0][h][kk], bf, acc[0][h]);
                acc[1][h] = MFMA16(af[1][h][kk], bf, acc[1][h]);
            }
            #pragma unroll
            for (int i = 0; i < 4; ++i) {
                int g = 2 + (i >> 1), h = i & 1;
                bf16x8 a = (kk & 1) ? s1[i] : s0[i];
                acc[g][h] = MFMA16(a, bf, acc[g][h]);
            }
        }

        // -- phase 2: cell update (regs) + write h_{t+1} --
        #pragma unroll
        for (int half = 0; half < 2; ++half) {
            float hh[4];
            #pragma unroll
            for (int r = 0; r < 4; ++r) {
                float iv = acc[0][half][r], fv = acc[1][half][r];
                float gv = acc[2][half][r], ov = acc[3][half][r];
                float cc = sigm(fv) * c[half][r] + sigm(iv) * tanh_f(gv);
                c[half][r] = cc;
                hh[r] = sigm(ov) * tanh_f(cc);
            }
            int dim = 32 * wv + 16 * half + 4 * quad;
            *(unsigned*)&nxt[l15][dim]     = pk2(hh[0], hh[1]);
            *(unsigned*)&nxt[l15][dim + 2] = pk2(hh[2], hh[3]);
        }
        __syncthreads();   // B1: h_{t+1} complete

        // -- phase 3: z = relu(h_{t+1} @ Wo1^T + bo1); wave wv -> z-dims [16wv,16wv+16) --
        {
            f32x4 za = zero4;
            #pragma unroll
            for (int kk = 0; kk < 9; ++kk) {
                int ko = 32 * kk + 8 * quad;
                bf16x8 a = *(const bf16x8*)&wo1l[16 * wv + l15][ko];
                bf16x8 b = *(const bf16x8*)&nxt[l15][ko];   // stale x cols harmless: Wo1ext=0 there
                za = MFMA16(a, b, za);
            }
            int zd = 16 * wv + 4 * quad;
            *(unsigned*)&zbuf[l15][zd]     = pk2(fmaxf(za[0], 0.f), fmaxf(za[1], 0.f));
            *(unsigned*)&zbuf[l15][zd + 2] = pk2(fmaxf(za[2], 0.f), fmaxf(za[3], 0.f));
        }
        __syncthreads();   // B2: z complete

        // -- phase 4 (wave 0): y = z @ Wo2^T + bo2; emit out + x_{t+1} --
        if (wv == 0) {
            f32x4 ya = zero4;
            #pragma unroll
            for (int kk = 0; kk < 4; ++kk) {
                int ko = 32 * kk + 8 * quad;
                ya = MFMA16(*(const bf16x8*)&wo2l[l15][ko],
                            *(const bf16x8*)&zbuf[l15][ko], ya);
            }
            if (quad == 0) {
                float y0 = ya[0] + bo2[0], y1 = ya[1] + bo2[1], y2 = ya[2] + bo2[2];
                float* op = out + ((size_t)(gb + l15) * TSTEPS + t) * 3;
                op[0] = y0; op[1] = y1; op[2] = y2;
                *(unsigned*)&nxt[l15][256] = pk2(y0, y1);
                *(unsigned*)&nxt[l15][258] = pk2(y2, 1.f);  // keep ones col = 1
            }
        }
        __syncthreads();   // B3: x_{t+1} visible
    }
}

extern "C" void kernel_launch(void* const* d_in, const int* in_sizes, int n_in,
                              void* d_out, int out_size, void* d_ws, size_t ws_size,
                              hipStream_t stream)
{
    const float* meta = (const float*)d_in[0];
    const float* W1   = (const float*)d_in[2];
    const float* b1   = (const float*)d_in[3];
    const float* W2   = (const float*)d_in[4];
    const float* b2   = (const float*)d_in[5];
    const float* Wih  = (const float*)d_in[6];
    const float* Whh  = (const float*)d_in[7];
    const float* bih  = (const float*)d_in[8];
    const float* bhh  = (const float*)d_in[9];
    const float* Wo1  = (const float*)d_in[10];
    const float* bo1  = (const float*)d_in[11];
    const float* Wo2  = (const float*)d_in[12];
    const float* bo2  = (const float*)d_in[13];
    bf16_t* ws  = (bf16_t*)d_ws;
    float*  out = (float*)d_out;

    prep_kernel<<<dim3((WS_ELEMS + 255) / 256), dim3(256), 0, stream>>>(
        W2, b2, Wih, Whh, bih, bhh, Wo1, bo1, Wo2, ws);
    lstm_main<<<dim3(4096 / TILE_B), dim3(512), 0, stream>>>(
        meta, W1, b1, bo2, ws, out);
}